// Round 1
// baseline (286.298 us; speedup 1.0000x reference)
//
#include <hip/hip_runtime.h>

// Masked MSE: out = sum((in-tgt)^2 * (mask==1)) / sum(mask==1)
// N = 32*3*512*512 = 25,165,824 (divisible by 4) -> float4/int4 loads.

#define BLOCK 256
#define GRID 2048

__global__ __launch_bounds__(BLOCK) void masked_mse_reduce(
    const float4* __restrict__ inp,
    const float4* __restrict__ tgt,
    const int4* __restrict__ msk,
    float* __restrict__ acc_sum,
    unsigned int* __restrict__ acc_cnt,
    int n4)
{
    int idx = blockIdx.x * blockDim.x + threadIdx.x;
    int stride = gridDim.x * blockDim.x;

    float s = 0.0f;
    unsigned int c = 0u;

    for (int i = idx; i < n4; i += stride) {
        float4 a = inp[i];
        float4 b = tgt[i];
        int4 m = msk[i];
        float d0 = a.x - b.x;
        float d1 = a.y - b.y;
        float d2 = a.z - b.z;
        float d3 = a.w - b.w;
        // mask values are 0 or 1; multiply instead of branch
        s += (float)m.x * d0 * d0;
        s += (float)m.y * d1 * d1;
        s += (float)m.z * d2 * d2;
        s += (float)m.w * d3 * d3;
        c += (unsigned int)(m.x + m.y + m.z + m.w);
    }

    // wave-64 shuffle reduction
    #pragma unroll
    for (int off = 32; off > 0; off >>= 1) {
        s += __shfl_down(s, off, 64);
        c += __shfl_down(c, off, 64);
    }

    // per-block LDS reduction across 4 waves
    __shared__ float ssum[BLOCK / 64];
    __shared__ unsigned int scnt[BLOCK / 64];
    int lane = threadIdx.x & 63;
    int wave = threadIdx.x >> 6;
    if (lane == 0) {
        ssum[wave] = s;
        scnt[wave] = c;
    }
    __syncthreads();
    if (threadIdx.x == 0) {
        float bs = 0.0f;
        unsigned int bc = 0u;
        #pragma unroll
        for (int w = 0; w < BLOCK / 64; ++w) {
            bs += ssum[w];
            bc += scnt[w];
        }
        atomicAdd(acc_sum, bs);
        atomicAdd(acc_cnt, bc);
    }
}

__global__ void masked_mse_finalize(const float* __restrict__ acc_sum,
                                    const unsigned int* __restrict__ acc_cnt,
                                    float* __restrict__ out)
{
    out[0] = acc_sum[0] / (float)acc_cnt[0];
}

extern "C" void kernel_launch(void* const* d_in, const int* in_sizes, int n_in,
                              void* d_out, int out_size, void* d_ws, size_t ws_size,
                              hipStream_t stream)
{
    const float4* inp = (const float4*)d_in[0];
    const float4* tgt = (const float4*)d_in[1];
    const int4* msk = (const int4*)d_in[2];
    int n = in_sizes[0];
    int n4 = n / 4;

    float* acc_sum = (float*)d_ws;
    unsigned int* acc_cnt = (unsigned int*)((char*)d_ws + sizeof(float));

    // workspace is poisoned 0xAA before every launch -> zero accumulators
    hipMemsetAsync(d_ws, 0, sizeof(float) + sizeof(unsigned int), stream);

    masked_mse_reduce<<<GRID, BLOCK, 0, stream>>>(inp, tgt, msk, acc_sum, acc_cnt, n4);
    masked_mse_finalize<<<1, 1, 0, stream>>>(acc_sum, acc_cnt, (float*)d_out);
}

// Round 2
// 284.091 us; speedup vs baseline: 1.0078x; 1.0078x over previous
//
#include <hip/hip_runtime.h>

// Masked MSE: out = sum((in-tgt)^2 * (mask==1)) / sum(mask==1)
// Memory-bound 3-stream reduction. Key optimization: UNROLL independent
// float4 loads per thread staged into registers before consumption ->
// 24 outstanding 16B loads per wave (MLP), instead of 3 with a plain
// grid-stride loop (which was latency-bound at 2.65 TB/s combined).

#define BLOCK 256
#define UNROLL 8

__global__ __launch_bounds__(BLOCK) void masked_mse_reduce(
    const float4* __restrict__ inp,
    const float4* __restrict__ tgt,
    const int4* __restrict__ msk,
    float* __restrict__ acc_sum,
    unsigned int* __restrict__ acc_cnt)
{
    // Flat tiling: block b covers [b*BLOCK*UNROLL, (b+1)*BLOCK*UNROLL) float4s.
    // Launch covers the divisible region exactly -> no per-load guards, so the
    // compiler hoists all 3*UNROLL loads before the first s_waitcnt.
    const long base = (long)blockIdx.x * (BLOCK * UNROLL) + threadIdx.x;

    float4 a[UNROLL];
    float4 b[UNROLL];
    int4 m[UNROLL];
#pragma unroll
    for (int u = 0; u < UNROLL; ++u) {
        const long i = base + (long)u * BLOCK;   // wave-coalesced per u
        a[u] = inp[i];
        b[u] = tgt[i];
        m[u] = msk[i];
    }

    float s = 0.0f;
    unsigned int c = 0u;
#pragma unroll
    for (int u = 0; u < UNROLL; ++u) {
        float d0 = a[u].x - b[u].x;
        float d1 = a[u].y - b[u].y;
        float d2 = a[u].z - b[u].z;
        float d3 = a[u].w - b[u].w;
        s += (float)m[u].x * d0 * d0;
        s += (float)m[u].y * d1 * d1;
        s += (float)m[u].z * d2 * d2;
        s += (float)m[u].w * d3 * d3;
        c += (unsigned int)(m[u].x + m[u].y + m[u].z + m[u].w);
    }

    // wave-64 shuffle reduction
#pragma unroll
    for (int off = 32; off > 0; off >>= 1) {
        s += __shfl_down(s, off, 64);
        c += __shfl_down(c, off, 64);
    }

    __shared__ float ssum[BLOCK / 64];
    __shared__ unsigned int scnt[BLOCK / 64];
    const int lane = threadIdx.x & 63;
    const int wave = threadIdx.x >> 6;
    if (lane == 0) {
        ssum[wave] = s;
        scnt[wave] = c;
    }
    __syncthreads();
    if (threadIdx.x == 0) {
        float bs = 0.0f;
        unsigned int bc = 0u;
#pragma unroll
        for (int w = 0; w < BLOCK / 64; ++w) {
            bs += ssum[w];
            bc += scnt[w];
        }
        atomicAdd(acc_sum, bs);
        atomicAdd(acc_cnt, bc);
    }
}

// Handles any elements not covered by the vectorized kernel (none for the
// reference shape, which divides exactly; kept for generality).
__global__ void masked_mse_tail(
    const float* __restrict__ inp,
    const float* __restrict__ tgt,
    const int* __restrict__ msk,
    float* __restrict__ acc_sum,
    unsigned int* __restrict__ acc_cnt,
    long start, long n)
{
    long i = start + blockIdx.x * (long)blockDim.x + threadIdx.x;
    float s = 0.0f;
    unsigned int c = 0u;
    for (; i < n; i += (long)gridDim.x * blockDim.x) {
        float d = inp[i] - tgt[i];
        int mv = msk[i];
        s += (float)mv * d * d;
        c += (unsigned int)mv;
    }
#pragma unroll
    for (int off = 32; off > 0; off >>= 1) {
        s += __shfl_down(s, off, 64);
        c += __shfl_down(c, off, 64);
    }
    if ((threadIdx.x & 63) == 0) {
        atomicAdd(acc_sum, s);
        atomicAdd(acc_cnt, c);
    }
}

__global__ void masked_mse_finalize(const float* __restrict__ acc_sum,
                                    const unsigned int* __restrict__ acc_cnt,
                                    float* __restrict__ out)
{
    out[0] = acc_sum[0] / (float)acc_cnt[0];
}

extern "C" void kernel_launch(void* const* d_in, const int* in_sizes, int n_in,
                              void* d_out, int out_size, void* d_ws, size_t ws_size,
                              hipStream_t stream)
{
    const float* inp = (const float*)d_in[0];
    const float* tgt = (const float*)d_in[1];
    const int* msk = (const int*)d_in[2];
    const long n = in_sizes[0];
    const long n4 = n / 4;

    float* acc_sum = (float*)d_ws;
    unsigned int* acc_cnt = (unsigned int*)((char*)d_ws + sizeof(float));

    hipMemsetAsync(d_ws, 0, 2 * sizeof(float), stream);

    const long per_block = (long)BLOCK * UNROLL;     // float4s per block
    const long nblocks = n4 / per_block;             // full blocks (3072 here)
    if (nblocks > 0) {
        masked_mse_reduce<<<(int)nblocks, BLOCK, 0, stream>>>(
            (const float4*)inp, (const float4*)tgt, (const int4*)msk,
            acc_sum, acc_cnt);
    }
    const long covered = nblocks * per_block * 4;    // elements covered
    if (covered < n) {
        masked_mse_tail<<<64, BLOCK, 0, stream>>>(
            inp, tgt, msk, acc_sum, acc_cnt, covered, n);
    }
    masked_mse_finalize<<<1, 1, 0, stream>>>(acc_sum, acc_cnt, (float*)d_out);
}